// Round 7
// baseline (324.846 us; speedup 1.0000x reference)
//
#include <hip/hip_runtime.h>
#include <stdint.h>

#define HIDDEN 1024
#define INTER  4096
#define ROWS   8192               // 4 * 2048
#define NKSTEP 64                 // INTER / 64
#define B_KSTEP 65536             // bytes per K-step in Bg (1024 cols x 64)
#define A_KSTEP 524288            // bytes per K-step in Ag (8192 rows x 64)

typedef int i32x4 __attribute__((ext_vector_type(4)));

// sign byte: +1 (0x01) for x>=0, -1 (0xFF) for x<0.
__device__ __forceinline__ uint32_t sgn4(float4 v) {
    uint32_t b0 = (v.x < 0.f) ? 0xFFu : 0x01u;
    uint32_t b1 = (v.y < 0.f) ? 0xFFu : 0x01u;
    uint32_t b2 = (v.z < 0.f) ? 0xFFu : 0x01u;
    uint32_t b3 = (v.w < 0.f) ? 0xFFu : 0x01u;
    return b0 | (b1 << 8) | (b2 << 16) | (b3 << 24);
}

// Frag-major layout (r2-proven, used for BOTH operands):
//   byte(i, k) = (k>>6)*KSTEP + (i>>4)*1024 + ((k&63)>>4)*256 + (i&15)*16 + (k&15)
// so the MFMA fragment for 16 rows/cols starting i0 at K-step t is the
// contiguous 1 KB at base + t*KSTEP + (i0>>4)*1024, element lane*16.

// ---------------------------------------------------------------------------
// K1: W [1024][4096] f32 -> Bg frag-major i8 signs + wscale[h]=mean(|W[h,:]|).
// ---------------------------------------------------------------------------
__global__ __launch_bounds__(256)
void pack_w_kernel(const float* __restrict__ W, uint8_t* __restrict__ Bg,
                   float* __restrict__ wscale) {
    int h = blockIdx.x;
    int tid = threadIdx.x;
    int lane = tid & 63, wv = tid >> 6;
    const float4* row = (const float4*)(W + (size_t)h * INTER);
    const uint32_t base_h = (uint32_t)(h >> 4) * 1024u + (uint32_t)(h & 15) * 16u;
    float asum = 0.f;
    #pragma unroll
    for (int q = 0; q < 4; ++q) {
        int g = q * 256 + tid;                 // float4 index 0..1023 (coalesced)
        float4 v = row[g];
        asum += fabsf(v.x) + fabsf(v.y) + fabsf(v.z) + fabsf(v.w);
        uint32_t off = (uint32_t)(g >> 4) * (uint32_t)B_KSTEP + base_h
                     + (uint32_t)((g & 15) >> 2) * 256u + (uint32_t)(g & 3) * 4u;
        *(uint32_t*)(Bg + off) = sgn4(v);
    }
    #pragma unroll
    for (int off = 32; off > 0; off >>= 1) asum += __shfl_down(asum, off);
    __shared__ float red[4];
    if (lane == 0) red[wv] = asum;
    __syncthreads();
    if (tid == 0) wscale[h] = (red[0] + red[1] + red[2] + red[3]) * (1.0f / INTER);
}

// ---------------------------------------------------------------------------
// K2: hs [8192][4096] f32 -> Ag frag-major i8 signs (same layout, A_KSTEP).
// One block per row; coalesced float4 reads, scattered 16B-granule writes.
// ---------------------------------------------------------------------------
__global__ __launch_bounds__(256)
void pack_a_kernel(const float* __restrict__ hs, uint8_t* __restrict__ Ag) {
    int m = blockIdx.x;
    int tid = threadIdx.x;
    const float4* row = (const float4*)(hs + (size_t)m * INTER);
    const uint32_t base_m = (uint32_t)(m >> 4) * 1024u + (uint32_t)(m & 15) * 16u;
    #pragma unroll
    for (int q = 0; q < 4; ++q) {
        int g = q * 256 + tid;                 // float4 index 0..1023 (coalesced)
        float4 v = row[g];
        uint32_t off = (uint32_t)(g >> 4) * (uint32_t)A_KSTEP + base_m
                     + (uint32_t)((g & 15) >> 2) * 256u + (uint32_t)(g & 3) * 4u;
        *(uint32_t*)(Ag + off) = sgn4(v);
    }
}

// ---------------------------------------------------------------------------
// K3: i8 MFMA GEMM with ZERO LDS and ZERO barriers. 512 blocks x 256 thr.
//   bid -> (ct = bid&7 = XCD, mt = bid>>3): each XCD owns one 128-col strip
//   of B (512 KB, L2-resident for the whole kernel) and streams all A strips.
//   Wave (wr = wave>>1, wc = wave&1) owns a 64x64 output tile: rows
//   mt*128 + wr*64, cols ct*128 + wc*64. Per K-step: 4 A-frag + 4 B-frag
//   contiguous-1KB register loads (2-deep double buffer, compiler-counted
//   vmcnt) + 16 MFMA. Waves fully independent -> latency hidden by occupancy,
//   no convoy effects.
//   Epilogue: y = clip*wscale*dot + bias + input -> out (pre-LN); K4 does LN.
// ---------------------------------------------------------------------------
__global__ __launch_bounds__(256, 3)
void gemm_kernel(const float* __restrict__ input, const float* __restrict__ bias,
                 const float* __restrict__ clipp, float* __restrict__ out,
                 const uint8_t* __restrict__ Ag, const uint8_t* __restrict__ Bg,
                 const float* __restrict__ wscale) {
    const int tid  = threadIdx.x;
    const int lane = tid & 63;
    const int wave = tid >> 6;
    const int ct   = blockIdx.x & 7;
    const int mt   = blockIdx.x >> 3;
    const int wr   = wave >> 1, wc = wave & 1;
    const int R0   = mt * 128 + wr * 64;
    const int C0   = ct * 128 + wc * 64;

    const uint8_t* aB = Ag + (size_t)(R0 >> 4) * 1024 + lane * 16;
    const uint8_t* bB = Bg + (size_t)(C0 >> 4) * 1024 + lane * 16;

    i32x4 acc[4][4];
    #pragma unroll
    for (int i = 0; i < 4; ++i)
        #pragma unroll
        for (int j = 0; j < 4; ++j) acc[i][j] = (i32x4){0, 0, 0, 0};

    i32x4 Af0[4], Bf0[4], Af1[4], Bf1[4];

    // prologue: K-step 0 into buffer 0
    #pragma unroll
    for (int u = 0; u < 4; ++u) {
        Af0[u] = *(const i32x4*)(aB + u * 1024);
        Bf0[u] = *(const i32x4*)(bB + u * 1024);
    }

// Compute tile T from buffer BC; prefetch T+1 into buffer BN_ (plain register
// loads -> compiler emits exact counted vmcnt; loads overlap the 16 MFMAs).
#define STEP(T, BC, BN_, PF) do {                                              \
    if (PF) {                                                                  \
        const uint8_t* ap_ = aB + (size_t)((T) + 1) * A_KSTEP;                 \
        const uint8_t* bp_ = bB + (size_t)((T) + 1) * B_KSTEP;                 \
        _Pragma("unroll")                                                      \
        for (int u_ = 0; u_ < 4; ++u_) {                                       \
            Af##BN_[u_] = *(const i32x4*)(ap_ + u_ * 1024);                    \
            Bf##BN_[u_] = *(const i32x4*)(bp_ + u_ * 1024);                    \
        }                                                                      \
    }                                                                          \
    __builtin_amdgcn_s_setprio(1);                                             \
    _Pragma("unroll")                                                          \
    for (int i_ = 0; i_ < 4; ++i_)                                             \
        _Pragma("unroll")                                                      \
        for (int j_ = 0; j_ < 4; ++j_)                                         \
            acc[i_][j_] = __builtin_amdgcn_mfma_i32_16x16x64_i8(               \
                Af##BC[i_], Bf##BC[j_], acc[i_][j_], 0, 0, 0);                 \
    __builtin_amdgcn_s_setprio(0);                                             \
} while (0)

    for (int tt = 0; tt < 31; ++tt) {
        STEP(2 * tt,     0, 1, 1);
        STEP(2 * tt + 1, 1, 0, 1);
    }
    STEP(62, 0, 1, 1);   // prefetch K-step 63
    STEP(63, 1, 0, 0);   // final
#undef STEP

    // ---- epilogue: y = clip*wscale*dot + bias + input -> out (pre-LN) ----
    const float clip = clipp[0];
    const int l15 = lane & 15;
    const int rb  = (lane >> 4) * 4;
    float cw[4], bi[4];
    #pragma unroll
    for (int j = 0; j < 4; ++j) {
        int gcol = C0 + j * 16 + l15;
        cw[j] = clip * wscale[gcol];
        bi[j] = bias[gcol];
    }
    #pragma unroll
    for (int i = 0; i < 4; ++i) {
        #pragma unroll
        for (int rg = 0; rg < 4; ++rg) {
            int row = R0 + i * 16 + rb + rg;
            #pragma unroll
            for (int j = 0; j < 4; ++j) {
                size_t gidx = (size_t)row * HIDDEN + C0 + j * 16 + l15;
                out[gidx] = fmaf((float)acc[i][j][rg], cw[j], bi[j] + input[gidx]);
            }
        }
    }
}

// ---------------------------------------------------------------------------
// K4: one-pass in-place LayerNorm. One row per wave (1024 f32 = 4 float4/lane).
// ---------------------------------------------------------------------------
__global__ __launch_bounds__(256)
void ln_kernel(float* __restrict__ out, const float* __restrict__ gamma,
               const float* __restrict__ beta) {
    const int lane = threadIdx.x & 63;
    const int wave = threadIdx.x >> 6;
    const int row  = blockIdx.x * 4 + wave;
    float4* rowp = (float4*)(out + (size_t)row * HIDDEN);
    const float4* gm4 = (const float4*)gamma;
    const float4* bt4 = (const float4*)beta;

    float4 v0 = rowp[lane +   0];
    float4 v1 = rowp[lane +  64];
    float4 v2 = rowp[lane + 128];
    float4 v3 = rowp[lane + 192];
    float s = v0.x + v0.y + v0.z + v0.w + v1.x + v1.y + v1.z + v1.w
            + v2.x + v2.y + v2.z + v2.w + v3.x + v3.y + v3.z + v3.w;
    float q = v0.x * v0.x + v0.y * v0.y + v0.z * v0.z + v0.w * v0.w
            + v1.x * v1.x + v1.y * v1.y + v1.z * v1.z + v1.w * v1.w
            + v2.x * v2.x + v2.y * v2.y + v2.z * v2.z + v2.w * v2.w
            + v3.x * v3.x + v3.y * v3.y + v3.z * v3.z + v3.w * v3.w;
    #pragma unroll
    for (int off = 1; off < 64; off <<= 1) {
        s += __shfl_xor(s, off);
        q += __shfl_xor(q, off);
    }
    float mu  = s * (1.0f / HIDDEN);
    float var = fmaf(-mu, mu, q * (1.0f / HIDDEN));
    float rs  = rsqrtf(var + 1e-12f);

    #pragma unroll
    for (int j = 0; j < 4; ++j) {
        int idx = lane + j * 64;
        float4 y = (j == 0) ? v0 : (j == 1) ? v1 : (j == 2) ? v2 : v3;
        float4 g = gm4[idx], b = bt4[idx];
        float4 o;
        o.x = (y.x - mu) * rs * g.x + b.x;
        o.y = (y.y - mu) * rs * g.y + b.y;
        o.z = (y.z - mu) * rs * g.z + b.z;
        o.w = (y.w - mu) * rs * g.w + b.w;
        rowp[idx] = o;
    }
}

// ---------------------------------------------------------------------------
extern "C" void kernel_launch(void* const* d_in, const int* in_sizes, int n_in,
                              void* d_out, int out_size, void* d_ws, size_t ws_size,
                              hipStream_t stream) {
    const float* hs    = (const float*)d_in[0];  // [4,2048,4096]
    const float* inp   = (const float*)d_in[1];  // [4,2048,1024]
    const float* W     = (const float*)d_in[2];  // [1024,4096]
    const float* b     = (const float*)d_in[3];  // [1024]
    const float* clip  = (const float*)d_in[4];  // scalar
    const float* gamma = (const float*)d_in[5];  // [1024]
    const float* beta  = (const float*)d_in[6];  // [1024]
    float* out = (float*)d_out;

    uint8_t* Bg   = (uint8_t*)d_ws;                                  // 4 MB
    uint8_t* Ag   = (uint8_t*)d_ws + (size_t)4 * 1024 * 1024;        // 32 MB
    float* wscale = (float*)((char*)d_ws + (size_t)36 * 1024 * 1024); // 4 KB

    pack_w_kernel<<<HIDDEN, 256, 0, stream>>>(W, Bg, wscale);
    pack_a_kernel<<<ROWS, 256, 0, stream>>>(hs, Ag);
    gemm_kernel<<<512, 256, 0, stream>>>(inp, b, clip, out, Ag, Bg, wscale);
    ln_kernel<<<ROWS / 4, 256, 0, stream>>>(out, gamma, beta);
}

// Round 8
// 309.746 us; speedup vs baseline: 1.0488x; 1.0488x over previous
//
#include <hip/hip_runtime.h>
#include <stdint.h>

#define HIDDEN 1024
#define INTER  4096
#define ROWS   8192               // 4 * 2048
#define NKSTEP 64                 // INTER / 64
#define B_KSTEP 65536             // bytes per K-step in Bg (1024 cols x 64)
#define A_KSTEP 524288            // bytes per K-step in Ag (8192 rows x 64)

typedef int i32x4 __attribute__((ext_vector_type(4)));

// sign byte: +1 (0x01) for x>=0, -1 (0xFF) for x<0.
__device__ __forceinline__ uint32_t sgn4(float4 v) {
    uint32_t b0 = (v.x < 0.f) ? 0xFFu : 0x01u;
    uint32_t b1 = (v.y < 0.f) ? 0xFFu : 0x01u;
    uint32_t b2 = (v.z < 0.f) ? 0xFFu : 0x01u;
    uint32_t b3 = (v.w < 0.f) ? 0xFFu : 0x01u;
    return b0 | (b1 << 8) | (b2 << 16) | (b3 << 24);
}

// Frag-major layout (r2-proven, both operands):
//   byte(i, k) = (k>>6)*KSTEP + (i>>4)*1024 + ((k&63)>>4)*256 + (i&15)*16 + (k&15)
// MFMA fragment for 16 rows/cols starting i0 at K-step t = contiguous 1 KB at
//   base + t*KSTEP + (i0>>4)*1024, element lane*16.
// Pack mapping (one wave = one full 1 KB frag per K-step, no partial lines):
//   lane l -> row i0 + (l>>2), k-chunk l&3; reads 4 float4 (64 B) of hs/W row,
//   writes one 16 B granule at (l&3)*256 + (l>>2)*16.

// ---------------------------------------------------------------------------
// K1: W [1024][4096] f32 -> Bg frag-major i8 signs + wscale[h]=mean(|W[h,:]|).
// 64 blocks x 512 thr; wave w packs K-steps w*8..w*8+7 for 16 rows.
// ---------------------------------------------------------------------------
__global__ __launch_bounds__(512)
void pack_w_kernel(const float* __restrict__ W, uint8_t* __restrict__ Bg,
                   float* __restrict__ wscale) {
    const int tid  = threadIdx.x;
    const int lane = tid & 63;
    const int wv   = tid >> 6;           // 8 waves
    const int h0   = blockIdx.x * 16;    // 64 blocks
    const int r    = lane >> 2;          // row within 16-group
    const int kc   = lane & 3;           // k-chunk within 64
    const float4* src = (const float4*)(W + (size_t)(h0 + r) * INTER);
    uint8_t* dst = Bg + (size_t)blockIdx.x * 1024 + kc * 256 + r * 16;
    float asum = 0.f;
    #pragma unroll
    for (int i = 0; i < 8; ++i) {
        int t = wv * 8 + i;
        float4 v0 = src[t * 16 + kc * 4 + 0];
        float4 v1 = src[t * 16 + kc * 4 + 1];
        float4 v2 = src[t * 16 + kc * 4 + 2];
        float4 v3 = src[t * 16 + kc * 4 + 3];
        asum += fabsf(v0.x) + fabsf(v0.y) + fabsf(v0.z) + fabsf(v0.w)
              + fabsf(v1.x) + fabsf(v1.y) + fabsf(v1.z) + fabsf(v1.w)
              + fabsf(v2.x) + fabsf(v2.y) + fabsf(v2.z) + fabsf(v2.w)
              + fabsf(v3.x) + fabsf(v3.y) + fabsf(v3.z) + fabsf(v3.w);
        i32x4 sg = (i32x4){(int)sgn4(v0), (int)sgn4(v1),
                           (int)sgn4(v2), (int)sgn4(v3)};
        *(i32x4*)(dst + (size_t)t * B_KSTEP) = sg;
    }
    // reduce the 4 kc-lanes of each row, then across 8 waves
    asum += __shfl_xor(asum, 1);
    asum += __shfl_xor(asum, 2);
    __shared__ float red[8][16];
    if (kc == 0) red[wv][r] = asum;
    __syncthreads();
    if (tid < 16) {
        float s = 0.f;
        #pragma unroll
        for (int j = 0; j < 8; ++j) s += red[j][tid];
        wscale[h0 + tid] = s * (1.0f / INTER);
    }
}

// ---------------------------------------------------------------------------
// K2: hs [8192][4096] f32 -> Ag frag-major i8 signs.
// 2048 blocks x 256 thr: bid -> (rg = bid>>2 row-group, kg = bid&3 K-quarter);
// wave w packs K-steps kg*16 + w*4 .. +3. Full-line writes only.
// ---------------------------------------------------------------------------
__global__ __launch_bounds__(256)
void pack_a_kernel(const float* __restrict__ hs, uint8_t* __restrict__ Ag) {
    const int tid  = threadIdx.x;
    const int lane = tid & 63;
    const int wv   = tid >> 6;           // 4 waves
    const int rg   = blockIdx.x >> 2;    // 512 row-groups
    const int kg   = blockIdx.x & 3;     // K-quarter
    const int r    = lane >> 2;
    const int kc   = lane & 3;
    const float4* src = (const float4*)(hs + (size_t)(rg * 16 + r) * INTER);
    uint8_t* dst = Ag + (size_t)rg * 1024 + kc * 256 + r * 16;
    #pragma unroll
    for (int i = 0; i < 4; ++i) {
        int t = kg * 16 + wv * 4 + i;
        float4 v0 = src[t * 16 + kc * 4 + 0];
        float4 v1 = src[t * 16 + kc * 4 + 1];
        float4 v2 = src[t * 16 + kc * 4 + 2];
        float4 v3 = src[t * 16 + kc * 4 + 3];
        i32x4 sg = (i32x4){(int)sgn4(v0), (int)sgn4(v1),
                           (int)sgn4(v2), (int)sgn4(v3)};
        *(i32x4*)(dst + (size_t)t * A_KSTEP) = sg;
    }
}

// ---------------------------------------------------------------------------
// K3: i8 MFMA GEMM with ZERO LDS and ZERO barriers (unchanged from r7).
//   bid -> (ct = bid&7 = XCD, mt = bid>>3); wave owns a 64x64 output tile;
//   per K-step: 4 A-frag + 4 B-frag contiguous-1KB register loads (2-deep
//   double buffer, compiler-counted vmcnt) + 16 MFMA. Waves independent.
// ---------------------------------------------------------------------------
__global__ __launch_bounds__(256, 3)
void gemm_kernel(const float* __restrict__ input, const float* __restrict__ bias,
                 const float* __restrict__ clipp, float* __restrict__ out,
                 const uint8_t* __restrict__ Ag, const uint8_t* __restrict__ Bg,
                 const float* __restrict__ wscale) {
    const int tid  = threadIdx.x;
    const int lane = tid & 63;
    const int wave = tid >> 6;
    const int ct   = blockIdx.x & 7;
    const int mt   = blockIdx.x >> 3;
    const int wr   = wave >> 1, wc = wave & 1;
    const int R0   = mt * 128 + wr * 64;
    const int C0   = ct * 128 + wc * 64;

    const uint8_t* aB = Ag + (size_t)(R0 >> 4) * 1024 + lane * 16;
    const uint8_t* bB = Bg + (size_t)(C0 >> 4) * 1024 + lane * 16;

    i32x4 acc[4][4];
    #pragma unroll
    for (int i = 0; i < 4; ++i)
        #pragma unroll
        for (int j = 0; j < 4; ++j) acc[i][j] = (i32x4){0, 0, 0, 0};

    i32x4 Af0[4], Bf0[4], Af1[4], Bf1[4];

    #pragma unroll
    for (int u = 0; u < 4; ++u) {
        Af0[u] = *(const i32x4*)(aB + u * 1024);
        Bf0[u] = *(const i32x4*)(bB + u * 1024);
    }

#define STEP(T, BC, BN_, PF) do {                                              \
    if (PF) {                                                                  \
        const uint8_t* ap_ = aB + (size_t)((T) + 1) * A_KSTEP;                 \
        const uint8_t* bp_ = bB + (size_t)((T) + 1) * B_KSTEP;                 \
        _Pragma("unroll")                                                      \
        for (int u_ = 0; u_ < 4; ++u_) {                                       \
            Af##BN_[u_] = *(const i32x4*)(ap_ + u_ * 1024);                    \
            Bf##BN_[u_] = *(const i32x4*)(bp_ + u_ * 1024);                    \
        }                                                                      \
    }                                                                          \
    __builtin_amdgcn_s_setprio(1);                                             \
    _Pragma("unroll")                                                          \
    for (int i_ = 0; i_ < 4; ++i_)                                             \
        _Pragma("unroll")                                                      \
        for (int j_ = 0; j_ < 4; ++j_)                                         \
            acc[i_][j_] = __builtin_amdgcn_mfma_i32_16x16x64_i8(               \
                Af##BC[i_], Bf##BC[j_], acc[i_][j_], 0, 0, 0);                 \
    __builtin_amdgcn_s_setprio(0);                                             \
} while (0)

    for (int tt = 0; tt < 31; ++tt) {
        STEP(2 * tt,     0, 1, 1);
        STEP(2 * tt + 1, 1, 0, 1);
    }
    STEP(62, 0, 1, 1);
    STEP(63, 1, 0, 0);
#undef STEP

    const float clip = clipp[0];
    const int l15 = lane & 15;
    const int rb  = (lane >> 4) * 4;
    float cw[4], bi[4];
    #pragma unroll
    for (int j = 0; j < 4; ++j) {
        int gcol = C0 + j * 16 + l15;
        cw[j] = clip * wscale[gcol];
        bi[j] = bias[gcol];
    }
    #pragma unroll
    for (int i = 0; i < 4; ++i) {
        #pragma unroll
        for (int rg = 0; rg < 4; ++rg) {
            int row = R0 + i * 16 + rb + rg;
            #pragma unroll
            for (int j = 0; j < 4; ++j) {
                size_t gidx = (size_t)row * HIDDEN + C0 + j * 16 + l15;
                out[gidx] = fmaf((float)acc[i][j][rg], cw[j], bi[j] + input[gidx]);
            }
        }
    }
}

// ---------------------------------------------------------------------------
// K4: one-pass in-place LayerNorm (unchanged from r7).
// ---------------------------------------------------------------------------
__global__ __launch_bounds__(256)
void ln_kernel(float* __restrict__ out, const float* __restrict__ gamma,
               const float* __restrict__ beta) {
    const int lane = threadIdx.x & 63;
    const int wave = threadIdx.x >> 6;
    const int row  = blockIdx.x * 4 + wave;
    float4* rowp = (float4*)(out + (size_t)row * HIDDEN);
    const float4* gm4 = (const float4*)gamma;
    const float4* bt4 = (const float4*)beta;

    float4 v0 = rowp[lane +   0];
    float4 v1 = rowp[lane +  64];
    float4 v2 = rowp[lane + 128];
    float4 v3 = rowp[lane + 192];
    float s = v0.x + v0.y + v0.z + v0.w + v1.x + v1.y + v1.z + v1.w
            + v2.x + v2.y + v2.z + v2.w + v3.x + v3.y + v3.z + v3.w;
    float q = v0.x * v0.x + v0.y * v0.y + v0.z * v0.z + v0.w * v0.w
            + v1.x * v1.x + v1.y * v1.y + v1.z * v1.z + v1.w * v1.w
            + v2.x * v2.x + v2.y * v2.y + v2.z * v2.z + v2.w * v2.w
            + v3.x * v3.x + v3.y * v3.y + v3.z * v3.z + v3.w * v3.w;
    #pragma unroll
    for (int off = 1; off < 64; off <<= 1) {
        s += __shfl_xor(s, off);
        q += __shfl_xor(q, off);
    }
    float mu  = s * (1.0f / HIDDEN);
    float var = fmaf(-mu, mu, q * (1.0f / HIDDEN));
    float rs  = rsqrtf(var + 1e-12f);

    #pragma unroll
    for (int j = 0; j < 4; ++j) {
        int idx = lane + j * 64;
        float4 y = (j == 0) ? v0 : (j == 1) ? v1 : (j == 2) ? v2 : v3;
        float4 g = gm4[idx], b = bt4[idx];
        float4 o;
        o.x = (y.x - mu) * rs * g.x + b.x;
        o.y = (y.y - mu) * rs * g.y + b.y;
        o.z = (y.z - mu) * rs * g.z + b.z;
        o.w = (y.w - mu) * rs * g.w + b.w;
        rowp[idx] = o;
    }
}

// ---------------------------------------------------------------------------
extern "C" void kernel_launch(void* const* d_in, const int* in_sizes, int n_in,
                              void* d_out, int out_size, void* d_ws, size_t ws_size,
                              hipStream_t stream) {
    const float* hs    = (const float*)d_in[0];  // [4,2048,4096]
    const float* inp   = (const float*)d_in[1];  // [4,2048,1024]
    const float* W     = (const float*)d_in[2];  // [1024,4096]
    const float* b     = (const float*)d_in[3];  // [1024]
    const float* clip  = (const float*)d_in[4];  // scalar
    const float* gamma = (const float*)d_in[5];  // [1024]
    const float* beta  = (const float*)d_in[6];  // [1024]
    float* out = (float*)d_out;

    uint8_t* Bg   = (uint8_t*)d_ws;                                   // 4 MB
    uint8_t* Ag   = (uint8_t*)d_ws + (size_t)4 * 1024 * 1024;         // 32 MB
    float* wscale = (float*)((char*)d_ws + (size_t)36 * 1024 * 1024); // 4 KB

    pack_w_kernel<<<HIDDEN / 16, 512, 0, stream>>>(W, Bg, wscale);
    pack_a_kernel<<<(ROWS / 16) * 4, 256, 0, stream>>>(hs, Ag);
    gemm_kernel<<<512, 256, 0, stream>>>(inp, b, clip, out, Ag, Bg, wscale);
    ln_kernel<<<ROWS / 4, 256, 0, stream>>>(out, gamma, beta);
}

// Round 9
// 301.697 us; speedup vs baseline: 1.0767x; 1.0267x over previous
//
#include <hip/hip_runtime.h>
#include <stdint.h>

#define HIDDEN 1024
#define INTER  4096
#define ROWS   8192               // 4 * 2048
#define NKSTEP 64                 // INTER / 64
#define B_KSTEP 65536             // bytes per K-step in Bg (1024 cols x 64)
#define A_KSTEP 524288            // bytes per K-step in Ag (8192 rows x 64)

typedef int i32x4 __attribute__((ext_vector_type(4)));

// sign byte: +1 (0x01) for x>=0, -1 (0xFF) for x<0.
__device__ __forceinline__ uint32_t sgn4(float4 v) {
    uint32_t b0 = (v.x < 0.f) ? 0xFFu : 0x01u;
    uint32_t b1 = (v.y < 0.f) ? 0xFFu : 0x01u;
    uint32_t b2 = (v.z < 0.f) ? 0xFFu : 0x01u;
    uint32_t b3 = (v.w < 0.f) ? 0xFFu : 0x01u;
    return b0 | (b1 << 8) | (b2 << 16) | (b3 << 24);
}

// Frag-major layout (r2-proven, both operands):
//   byte(i, k) = (k>>6)*KSTEP + (i>>4)*1024 + ((k&63)>>4)*256 + (i&15)*16 + (k&15)
// MFMA fragment for 16 rows/cols starting i0 at K-step t = contiguous 1 KB at
//   base + t*KSTEP + (i0>>4)*1024, element lane*16.
// Pack mapping (one wave = one full 1 KB frag per K-step, no partial lines):
//   lane l -> row i0 + (l>>2), k-chunk l&3; reads 4 float4 (64 B) of the row,
//   writes one 16 B granule at (l&3)*256 + (l>>2)*16.

// ---------------------------------------------------------------------------
// K1: W [1024][4096] f32 -> Bg frag-major i8 signs + wscale[h]=mean(|W[h,:]|).
// 64 blocks x 512 thr; wave w packs K-steps w*8..w*8+7 for 16 rows.
// ---------------------------------------------------------------------------
__global__ __launch_bounds__(512)
void pack_w_kernel(const float* __restrict__ W, uint8_t* __restrict__ Bg,
                   float* __restrict__ wscale) {
    const int tid  = threadIdx.x;
    const int lane = tid & 63;
    const int wv   = tid >> 6;           // 8 waves
    const int h0   = blockIdx.x * 16;    // 64 blocks
    const int r    = lane >> 2;          // row within 16-group
    const int kc   = lane & 3;           // k-chunk within 64
    const float4* src = (const float4*)(W + (size_t)(h0 + r) * INTER);
    uint8_t* dst = Bg + (size_t)blockIdx.x * 1024 + kc * 256 + r * 16;
    float asum = 0.f;
    #pragma unroll
    for (int i = 0; i < 8; ++i) {
        int t = wv * 8 + i;
        float4 v0 = src[t * 16 + kc * 4 + 0];
        float4 v1 = src[t * 16 + kc * 4 + 1];
        float4 v2 = src[t * 16 + kc * 4 + 2];
        float4 v3 = src[t * 16 + kc * 4 + 3];
        asum += fabsf(v0.x) + fabsf(v0.y) + fabsf(v0.z) + fabsf(v0.w)
              + fabsf(v1.x) + fabsf(v1.y) + fabsf(v1.z) + fabsf(v1.w)
              + fabsf(v2.x) + fabsf(v2.y) + fabsf(v2.z) + fabsf(v2.w)
              + fabsf(v3.x) + fabsf(v3.y) + fabsf(v3.z) + fabsf(v3.w);
        i32x4 sg = (i32x4){(int)sgn4(v0), (int)sgn4(v1),
                           (int)sgn4(v2), (int)sgn4(v3)};
        *(i32x4*)(dst + (size_t)t * B_KSTEP) = sg;
    }
    asum += __shfl_xor(asum, 1);
    asum += __shfl_xor(asum, 2);
    __shared__ float red[8][16];
    if (kc == 0) red[wv][r] = asum;
    __syncthreads();
    if (tid < 16) {
        float s = 0.f;
        #pragma unroll
        for (int j = 0; j < 8; ++j) s += red[j][tid];
        wscale[h0 + tid] = s * (1.0f / INTER);
    }
}

// ---------------------------------------------------------------------------
// K2: hs [8192][4096] f32 -> Ag frag-major i8 signs. Full-line writes only.
// 2048 blocks x 256 thr: bid -> (rg = bid>>2, kg = bid&3 K-quarter).
// ---------------------------------------------------------------------------
__global__ __launch_bounds__(256)
void pack_a_kernel(const float* __restrict__ hs, uint8_t* __restrict__ Ag) {
    const int tid  = threadIdx.x;
    const int lane = tid & 63;
    const int wv   = tid >> 6;           // 4 waves
    const int rg   = blockIdx.x >> 2;    // 512 row-groups
    const int kg   = blockIdx.x & 3;     // K-quarter
    const int r    = lane >> 2;
    const int kc   = lane & 3;
    const float4* src = (const float4*)(hs + (size_t)(rg * 16 + r) * INTER);
    uint8_t* dst = Ag + (size_t)rg * 1024 + kc * 256 + r * 16;
    #pragma unroll
    for (int i = 0; i < 4; ++i) {
        int t = kg * 16 + wv * 4 + i;
        float4 v0 = src[t * 16 + kc * 4 + 0];
        float4 v1 = src[t * 16 + kc * 4 + 1];
        float4 v2 = src[t * 16 + kc * 4 + 2];
        float4 v3 = src[t * 16 + kc * 4 + 3];
        i32x4 sg = (i32x4){(int)sgn4(v0), (int)sgn4(v1),
                           (int)sgn4(v2), (int)sgn4(v3)};
        *(i32x4*)(dst + (size_t)t * A_KSTEP) = sg;
    }
}

// ---------------------------------------------------------------------------
// K3: i8 MFMA GEMM, zero LDS / zero barriers (r7-proven loop).
//   NEW partition: XCD owns a ROW stripe, not a column strip.
//   bid -> xcd = bid&7, sub = bid>>3; mt = xcd*8 + (sub>>3), ct = sub&7.
//   Per XCD: A slice 4 MB + B 4 MB = 8 MB working set (vs 32 MB before);
//   chip-wide L3 traffic 64 MB (4x less). Each A panel is shared by the 8
//   co-resident ct-blocks via L2; same for B panels across mt-blocks.
//   Wave (wr,wc) owns a 64x64 tile; per K-step: 4 A-frag + 4 B-frag
//   contiguous-1KB register loads (2-deep dbuf, compiler-counted vmcnt),
//   16 MFMA. Waves fully independent.
// ---------------------------------------------------------------------------
__global__ __launch_bounds__(256, 3)
void gemm_kernel(const float* __restrict__ input, const float* __restrict__ bias,
                 const float* __restrict__ clipp, float* __restrict__ out,
                 const uint8_t* __restrict__ Ag, const uint8_t* __restrict__ Bg,
                 const float* __restrict__ wscale) {
    const int tid  = threadIdx.x;
    const int lane = tid & 63;
    const int wave = tid >> 6;
    const int xcd  = blockIdx.x & 7;
    const int sub  = blockIdx.x >> 3;
    const int mt   = xcd * 8 + (sub >> 3);     // 0..63
    const int ct   = sub & 7;                  // 0..7
    const int wr   = wave >> 1, wc = wave & 1;
    const int R0   = mt * 128 + wr * 64;
    const int C0   = ct * 128 + wc * 64;

    const uint8_t* aB = Ag + (size_t)(R0 >> 4) * 1024 + lane * 16;
    const uint8_t* bB = Bg + (size_t)(C0 >> 4) * 1024 + lane * 16;

    i32x4 acc[4][4];
    #pragma unroll
    for (int i = 0; i < 4; ++i)
        #pragma unroll
        for (int j = 0; j < 4; ++j) acc[i][j] = (i32x4){0, 0, 0, 0};

    i32x4 Af0[4], Bf0[4], Af1[4], Bf1[4];

    #pragma unroll
    for (int u = 0; u < 4; ++u) {
        Af0[u] = *(const i32x4*)(aB + u * 1024);
        Bf0[u] = *(const i32x4*)(bB + u * 1024);
    }

#define STEP(T, BC, BN_, PF) do {                                              \
    if (PF) {                                                                  \
        const uint8_t* ap_ = aB + (size_t)((T) + 1) * A_KSTEP;                 \
        const uint8_t* bp_ = bB + (size_t)((T) + 1) * B_KSTEP;                 \
        _Pragma("unroll")                                                      \
        for (int u_ = 0; u_ < 4; ++u_) {                                       \
            Af##BN_[u_] = *(const i32x4*)(ap_ + u_ * 1024);                    \
            Bf##BN_[u_] = *(const i32x4*)(bp_ + u_ * 1024);                    \
        }                                                                      \
    }                                                                          \
    __builtin_amdgcn_s_setprio(1);                                             \
    _Pragma("unroll")                                                          \
    for (int i_ = 0; i_ < 4; ++i_)                                             \
        _Pragma("unroll")                                                      \
        for (int j_ = 0; j_ < 4; ++j_)                                         \
            acc[i_][j_] = __builtin_amdgcn_mfma_i32_16x16x64_i8(               \
                Af##BC[i_], Bf##BC[j_], acc[i_][j_], 0, 0, 0);                 \
    __builtin_amdgcn_s_setprio(0);                                             \
} while (0)

    for (int tt = 0; tt < 31; ++tt) {
        STEP(2 * tt,     0, 1, 1);
        STEP(2 * tt + 1, 1, 0, 1);
    }
    STEP(62, 0, 1, 1);
    STEP(63, 1, 0, 0);
#undef STEP

    const float clip = clipp[0];
    const int l15 = lane & 15;
    const int rb  = (lane >> 4) * 4;
    float cw[4], bi[4];
    #pragma unroll
    for (int j = 0; j < 4; ++j) {
        int gcol = C0 + j * 16 + l15;
        cw[j] = clip * wscale[gcol];
        bi[j] = bias[gcol];
    }
    #pragma unroll
    for (int i = 0; i < 4; ++i) {
        #pragma unroll
        for (int rg = 0; rg < 4; ++rg) {
            int row = R0 + i * 16 + rb + rg;
            #pragma unroll
            for (int j = 0; j < 4; ++j) {
                size_t gidx = (size_t)row * HIDDEN + C0 + j * 16 + l15;
                out[gidx] = fmaf((float)acc[i][j][rg], cw[j], bi[j] + input[gidx]);
            }
        }
    }
}

// ---------------------------------------------------------------------------
// K4: one-pass in-place LayerNorm. One row per wave.
// ---------------------------------------------------------------------------
__global__ __launch_bounds__(256)
void ln_kernel(float* __restrict__ out, const float* __restrict__ gamma,
               const float* __restrict__ beta) {
    const int lane = threadIdx.x & 63;
    const int wave = threadIdx.x >> 6;
    const int row  = blockIdx.x * 4 + wave;
    float4* rowp = (float4*)(out + (size_t)row * HIDDEN);
    const float4* gm4 = (const float4*)gamma;
    const float4* bt4 = (const float4*)beta;

    float4 v0 = rowp[lane +   0];
    float4 v1 = rowp[lane +  64];
    float4 v2 = rowp[lane + 128];
    float4 v3 = rowp[lane + 192];
    float s = v0.x + v0.y + v0.z + v0.w + v1.x + v1.y + v1.z + v1.w
            + v2.x + v2.y + v2.z + v2.w + v3.x + v3.y + v3.z + v3.w;
    float q = v0.x * v0.x + v0.y * v0.y + v0.z * v0.z + v0.w * v0.w
            + v1.x * v1.x + v1.y * v1.y + v1.z * v1.z + v1.w * v1.w
            + v2.x * v2.x + v2.y * v2.y + v2.z * v2.z + v2.w * v2.w
            + v3.x * v3.x + v3.y * v3.y + v3.z * v3.z + v3.w * v3.w;
    #pragma unroll
    for (int off = 1; off < 64; off <<= 1) {
        s += __shfl_xor(s, off);
        q += __shfl_xor(q, off);
    }
    float mu  = s * (1.0f / HIDDEN);
    float var = fmaf(-mu, mu, q * (1.0f / HIDDEN));
    float rs  = rsqrtf(var + 1e-12f);

    #pragma unroll
    for (int j = 0; j < 4; ++j) {
        int idx = lane + j * 64;
        float4 y = (j == 0) ? v0 : (j == 1) ? v1 : (j == 2) ? v2 : v3;
        float4 g = gm4[idx], b = bt4[idx];
        float4 o;
        o.x = (y.x - mu) * rs * g.x + b.x;
        o.y = (y.y - mu) * rs * g.y + b.y;
        o.z = (y.z - mu) * rs * g.z + b.z;
        o.w = (y.w - mu) * rs * g.w + b.w;
        rowp[idx] = o;
    }
}

// ---------------------------------------------------------------------------
extern "C" void kernel_launch(void* const* d_in, const int* in_sizes, int n_in,
                              void* d_out, int out_size, void* d_ws, size_t ws_size,
                              hipStream_t stream) {
    const float* hs    = (const float*)d_in[0];  // [4,2048,4096]
    const float* inp   = (const float*)d_in[1];  // [4,2048,1024]
    const float* W     = (const float*)d_in[2];  // [1024,4096]
    const float* b     = (const float*)d_in[3];  // [1024]
    const float* clip  = (const float*)d_in[4];  // scalar
    const float* gamma = (const float*)d_in[5];  // [1024]
    const float* beta  = (const float*)d_in[6];  // [1024]
    float* out = (float*)d_out;

    uint8_t* Bg   = (uint8_t*)d_ws;                                   // 4 MB
    uint8_t* Ag   = (uint8_t*)d_ws + (size_t)4 * 1024 * 1024;         // 32 MB
    float* wscale = (float*)((char*)d_ws + (size_t)36 * 1024 * 1024); // 4 KB

    pack_w_kernel<<<HIDDEN / 16, 512, 0, stream>>>(W, Bg, wscale);
    pack_a_kernel<<<(ROWS / 16) * 4, 256, 0, stream>>>(hs, Ag);
    gemm_kernel<<<512, 256, 0, stream>>>(inp, b, clip, out, Ag, Bg, wscale);
    ln_kernel<<<ROWS / 4, 256, 0, stream>>>(out, gamma, beta);
}